// Round 4
// baseline (483.816 us; speedup 1.0000x reference)
//
#include <hip/hip_runtime.h>

typedef unsigned short ushort_t;
typedef __attribute__((ext_vector_type(8))) short short8;
typedef __attribute__((ext_vector_type(4))) float f32x4;
typedef __attribute__((ext_vector_type(4))) unsigned int uint4v;

__device__ __forceinline__ ushort_t f2bf(float f) {
  union { float f; unsigned int u; } v; v.f = f;
  unsigned int u = v.u;
  unsigned int r = (u + 0x7fffu + ((u >> 16) & 1u)) >> 16;
  return (ushort_t)r;
}

// pack two f32 -> dword of two truncated bf16 (lo from 'lo', hi from 'hi')
__device__ __forceinline__ unsigned int pk2(float hi, float lo) {
  union { float f; unsigned int u; } a, b; a.f = lo; b.f = hi;
  return __builtin_amdgcn_perm(b.u, a.u, 0x07060302u);
}

__device__ __forceinline__ void load_lds16(const void* g, void* l) {
  __builtin_amdgcn_global_load_lds(
      (const __attribute__((address_space(1))) unsigned int*)g,
      (__attribute__((address_space(3))) unsigned int*)l, 16, 0, 0);
}

// ---------------- elementwise f32 -> bf16 ----------------
__global__ __launch_bounds__(256) void cvt_f32_to_bf16_vec(
    const float* __restrict__ in, ushort_t* __restrict__ out, int n8) {
  int i = blockIdx.x * 256 + threadIdx.x;
  if (i >= n8) return;
  const float4* p = (const float4*)in;
  float4 a = p[2 * i];
  float4 b = p[2 * i + 1];
  short8 v;
  v[0] = (short)f2bf(a.x); v[1] = (short)f2bf(a.y);
  v[2] = (short)f2bf(a.z); v[3] = (short)f2bf(a.w);
  v[4] = (short)f2bf(b.x); v[5] = (short)f2bf(b.y);
  v[6] = (short)f2bf(b.z); v[7] = (short)f2bf(b.w);
  *(short8*)(out + (size_t)i * 8) = v;
}

// ---------------- transpose f32 [R][C] -> bf16 [C][R] ----------------
__global__ __launch_bounds__(256) void transpose_to_bf16(
    const float* __restrict__ in, ushort_t* __restrict__ out, int R, int C) {
  __shared__ float tile[64][65];
  int c0 = blockIdx.x * 64, r0 = blockIdx.y * 64;
  int tid = threadIdx.x;
  for (int it = 0; it < 16; ++it) {
    int l = it * 256 + tid;
    int r = l >> 6, c = l & 63;
    tile[r][c] = in[(size_t)(r0 + r) * C + c0 + c];
  }
  __syncthreads();
  for (int it = 0; it < 16; ++it) {
    int l = it * 256 + tid;
    int ro = l >> 6, co = l & 63;
    out[(size_t)(c0 + ro) * R + r0 + co] = f2bf(tile[co][ro]);
  }
}

// ---------------- m97-style gemm_bt core: C[128x128] = A[M][K] * Bt[N][K]^T ----
__device__ __forceinline__ void gemm_bt_main(
    const ushort_t* __restrict__ A, const ushort_t* __restrict__ Bt,
    int K, int bm, int bn, ushort_t* lds, f32x4 acc[4][4]) {
  const int tid = threadIdx.x;
  const int wave = tid >> 6, lane = tid & 63;
  const int quad = lane >> 4, col = lane & 15;
  const int wm = (wave & 1) * 64, wn = (wave >> 1) * 64;
  ushort_t* ldsA = lds;
  ushort_t* ldsB = lds + 8192;
  f32x4 z = {0.f, 0.f, 0.f, 0.f};
  for (int i = 0; i < 4; ++i)
    for (int j = 0; j < 4; ++j) acc[i][j] = z;
  for (int bk = 0; bk < K; bk += 64) {
    for (int is = 0; is < 4; ++is) {
      int o = is * 4096 + wave * 1024 + lane * 16;  // byte offset in 16KB tile
      int p = o >> 13;
      int w = o & 8191;
      int r = w >> 6, kk = (w & 63) >> 1;
      int ldso = (is * 4096 + wave * 1024) >> 1;  // uniform elem offset
      const ushort_t* ga = A + (size_t)(bm + r) * K + bk + p * 32 + kk;
      load_lds16(ga, ldsA + ldso);
      const ushort_t* gb = Bt + (size_t)(bn + r) * K + bk + p * 32 + kk;
      load_lds16(gb, ldsB + ldso);
    }
    __syncthreads();
    for (int ks = 0; ks < 2; ++ks) {
      short8 af[4], bfr[4];
      for (int i = 0; i < 4; ++i)
        af[i] = *(const short8*)(ldsA + ks * 4096 + (wm + i * 16 + col) * 32 + quad * 8);
      for (int j = 0; j < 4; ++j)
        bfr[j] = *(const short8*)(ldsB + ks * 4096 + (wn + j * 16 + col) * 32 + quad * 8);
      for (int i = 0; i < 4; ++i)
        for (int j = 0; j < 4; ++j)
          acc[i][j] = __builtin_amdgcn_mfma_f32_16x16x32_bf16(af[i], bfr[j], acc[i][j], 0, 0, 0);
    }
    __syncthreads();
  }
}

// ---------------- GEMM1: X*W1t^T + b, 128x256 tile (A shared across 2 n-tiles)
// -> Q(scaled) [bh][t][64], K [bh][t][64], Vt [bh][64][t]
// Q pre-scaled by 0.125*log2(e) for exp2-domain softmax.
__global__ __launch_bounds__(256, 2) void gemm_qkv(
    const ushort_t* __restrict__ Xb, const ushort_t* __restrict__ W1t,
    const float* __restrict__ bias, ushort_t* __restrict__ Qb,
    ushort_t* __restrict__ Kb, ushort_t* __restrict__ Vtb) {
  __shared__ ushort_t lds[24576];  // A 8192 elems (16KB) + B 16384 elems (32KB)
  const int K = 1024;
  const int ntile = 3072 / 256;  // 12
  const int bn = (blockIdx.x % ntile) * 256;
  const int bm = (blockIdx.x / ntile) * 128;
  const int tid = threadIdx.x;
  const int wave = tid >> 6, lane = tid & 63;
  const int quad = lane >> 4, col = lane & 15;
  const int wm = (wave & 1) * 64;       // 64-row half of the 128-row m-tile
  const int wn = (wave >> 1) * 128;     // 128-col half of the 256-col n-tile
  ushort_t* ldsA = lds;
  ushort_t* ldsB = lds + 8192;
  f32x4 z = {0.f, 0.f, 0.f, 0.f};
  f32x4 acc[4][8];
  for (int i = 0; i < 4; ++i)
    for (int j = 0; j < 8; ++j) acc[i][j] = z;

  for (int bk = 0; bk < K; bk += 64) {
    // A tile: 128 rows x 64 k, split planes [2][128][32]
#pragma unroll
    for (int is = 0; is < 4; ++is) {
      int o = is * 4096 + wave * 1024 + lane * 16;
      int p = o >> 13, w = o & 8191;
      int r = w >> 6, kk = (w & 63) >> 1;
      int ldso = (is * 4096 + wave * 1024) >> 1;
      load_lds16(Xb + (size_t)(bm + r) * K + bk + p * 32 + kk, ldsA + ldso);
    }
    // B tile: 256 rows x 64 k, split planes [2][256][32]
#pragma unroll
    for (int is = 0; is < 8; ++is) {
      int o = is * 4096 + wave * 1024 + lane * 16;
      int p = o >> 14, w = o & 16383;
      int r = w >> 6, kk = (w & 63) >> 1;
      int ldso = (is * 4096 + wave * 1024) >> 1;
      load_lds16(W1t + (size_t)(bn + r) * K + bk + p * 32 + kk, ldsB + ldso);
    }
    __syncthreads();
#pragma unroll
    for (int ks = 0; ks < 2; ++ks) {
      short8 af[4], bfr[8];
      for (int i = 0; i < 4; ++i)
        af[i] = *(const short8*)(ldsA + ks * 4096 + (wm + i * 16 + col) * 32 + quad * 8);
      for (int j = 0; j < 8; ++j)
        bfr[j] = *(const short8*)(ldsB + ks * 8192 + (wn + j * 16 + col) * 32 + quad * 8);
      for (int i = 0; i < 4; ++i)
        for (int j = 0; j < 8; ++j)
          acc[i][j] = __builtin_amdgcn_mfma_f32_16x16x32_bf16(af[i], bfr[j], acc[i][j], 0, 0, 0);
    }
    __syncthreads();
  }

  const float SCL = 0.18033688011112042f;  // 0.125 * log2(e)
  const int which = bn >> 10;  // 0=q, 1=k, 2=v (uniform per block: 4 ntiles each)
  for (int i = 0; i < 4; ++i) {
    int row0 = bm + wm + i * 16 + quad * 4;
    int b = row0 >> 11, t0 = row0 & 2047;
    for (int j = 0; j < 8; ++j) {
      int cg = bn + wn + j * 16 + col;
      float bv = bias[cg];
      int rem = cg & 1023;
      int h = rem >> 6, hd = rem & 63;
      size_t bh = (size_t)(b * 16 + h);
      if (which == 0) {
        for (int r = 0; r < 4; ++r)
          Qb[(bh * 2048 + t0 + r) * 64 + hd] = f2bf((acc[i][j][r] + bv) * SCL);
      } else if (which == 1) {
        for (int r = 0; r < 4; ++r)
          Kb[(bh * 2048 + t0 + r) * 64 + hd] = f2bf(acc[i][j][r] + bv);
      } else {
        ushort4 pk;
        pk.x = f2bf(acc[i][j][0] + bv);
        pk.y = f2bf(acc[i][j][1] + bv);
        pk.z = f2bf(acc[i][j][2] + bv);
        pk.w = f2bf(acc[i][j][3] + bv);
        *(ushort4*)(Vtb + (bh * 64 + hd) * 2048 + t0) = pk;
      }
    }
  }
}

// ---------------- GEMM2: Y*W2t^T + b -> out (fp32) ----------------
__global__ __launch_bounds__(256) void gemm_out_k(
    const ushort_t* __restrict__ Yb, const ushort_t* __restrict__ W2t,
    const float* __restrict__ bias, float* __restrict__ out) {
  __shared__ ushort_t lds[16384];
  const int ntile = 1024 / 128;
  int bn = (blockIdx.x % ntile) * 128;
  int bm = (blockIdx.x / ntile) * 128;
  f32x4 acc[4][4];
  gemm_bt_main(Yb, W2t, 1024, bm, bn, lds, acc);
  const int tid = threadIdx.x, wave = tid >> 6, lane = tid & 63;
  const int quad = lane >> 4, col = lane & 15;
  const int wm = (wave & 1) * 64, wn = (wave >> 1) * 64;
  for (int i = 0; i < 4; ++i) {
    int row0 = bm + wm + i * 16 + quad * 4;
    for (int j = 0; j < 4; ++j) {
      int cg = bn + wn + j * 16 + col;
      float bv = bias[cg];
      for (int r = 0; r < 4; ++r)
        out[(size_t)(row0 + r) * 1024 + cg] = acc[i][j][r] + bv;
    }
  }
}

// ---------------- flash attention, transposed-S, balanced persistent ----------
// Q(pre-scaled),K: [bh][2048][64] bf16; Vt: [bh][64][2048] bf16; Y: [b][t][1024].
// 512 blocks; block (a=blk>>6, bh=blk&63) processes q-tile 15-a then q-tile a
// => exactly 17 k-tiles per block (perfect balance, all resident).
// K/V tile kt+1 prefetched into registers during compute of kt.
// S^T = K*Q^T; P^T feeds PV as B-operand via permuted-k contraction;
// V staged into LDS pre-permuted (verified R2/R3).
#define KS_OFF 0      // K tile [128][72] elems
#define VS_OFF 9216   // V tile [64][136] elems, k-permuted within 32-groups
__global__ __launch_bounds__(256, 2) void attn(
    const ushort_t* __restrict__ Qb, const ushort_t* __restrict__ Kb,
    const ushort_t* __restrict__ Vtb, ushort_t* __restrict__ Yb) {
  __shared__ ushort_t lds[17920];  // 35840 B
  const int tid = threadIdx.x, wave = tid >> 6, lane = tid & 63;
  const int quad = lane >> 4, col = lane & 15;
  const int bh = blockIdx.x & 63;
  const int a = blockIdx.x >> 6;  // 0..7
  const int b = bh >> 4, h = bh & 15;
  const ushort_t* Qg = Qb + (size_t)bh * 2048 * 64;
  const ushort_t* Kg = Kb + (size_t)bh * 2048 * 64;
  const ushort_t* Vg = Vtb + (size_t)bh * 64 * 2048;
  const int kv = tid;
  f32x4 z = {0.f, 0.f, 0.f, 0.f};

  for (int item = 0; item < 2; ++item) {
    const int qt = item == 0 ? 15 - a : a;
    const int q0 = qt * 128;
    short8 qf[2][2];
    for (int i = 0; i < 2; ++i)
      for (int ks = 0; ks < 2; ++ks)
        qf[i][ks] = *(const short8*)(
            Qg + (size_t)(q0 + wave * 32 + i * 16 + col) * 64 + ks * 32 + quad * 8);
    short8 kpre[4], vpre[4];
#pragma unroll
    for (int it = 0; it < 4; ++it) {
      int v = it * 256 + kv;
      kpre[it] = *(const short8*)(Kg + (size_t)(0 + (v >> 3)) * 64 + (v & 7) * 8);
      vpre[it] = *(const short8*)(Vg + (size_t)(v >> 4) * 2048 + 0 + (v & 15) * 8);
    }

    f32x4 oacc[2][4];
    float mst[2] = {-3.0e38f, -3.0e38f}, lst[2] = {0.f, 0.f};
    for (int i = 0; i < 2; ++i)
      for (int dt = 0; dt < 4; ++dt) oacc[i][dt] = z;

    for (int kt = 0; kt <= qt; ++kt) {
      int k0 = kt * 128;
      __syncthreads();
#pragma unroll
      for (int it = 0; it < 4; ++it) {
        int v = it * 256 + kv;
        *(short8*)(lds + KS_OFF + (v >> 3) * 72 + (v & 7) * 8) = kpre[it];
      }
#pragma unroll
      for (int it = 0; it < 4; ++it) {
        int v = it * 256 + kv;
        int d = v >> 4, kc = (v & 15) * 8;
        int p = kc >> 5, u = (kc >> 4) & 1, g0 = (kc >> 2) & 3;
        int pos1 = p * 32 + g0 * 8 + u * 4;
        short8 val = vpre[it];
        ushort4 lo4, hi4;
        lo4.x = (ushort_t)val[0]; lo4.y = (ushort_t)val[1];
        lo4.z = (ushort_t)val[2]; lo4.w = (ushort_t)val[3];
        hi4.x = (ushort_t)val[4]; hi4.y = (ushort_t)val[5];
        hi4.z = (ushort_t)val[6]; hi4.w = (ushort_t)val[7];
        *(ushort4*)(lds + VS_OFF + d * 136 + pos1) = lo4;
        *(ushort4*)(lds + VS_OFF + d * 136 + pos1 + 8) = hi4;
      }
      __syncthreads();
      if (kt < qt) {
        int k0n = k0 + 128;
#pragma unroll
        for (int it = 0; it < 4; ++it) {
          int v = it * 256 + kv;
          kpre[it] = *(const short8*)(Kg + (size_t)(k0n + (v >> 3)) * 64 + (v & 7) * 8);
          vpre[it] = *(const short8*)(Vg + (size_t)(v >> 4) * 2048 + k0n + (v & 15) * 8);
        }
      }
      f32x4 s[2][8];
      for (int i = 0; i < 2; ++i)
        for (int j = 0; j < 8; ++j) s[i][j] = z;
      for (int j = 0; j < 8; ++j) {
        short8 kf0 = *(const short8*)(lds + KS_OFF + (j * 16 + col) * 72 + quad * 8);
        short8 kf1 = *(const short8*)(lds + KS_OFF + (j * 16 + col) * 72 + 32 + quad * 8);
        for (int i = 0; i < 2; ++i) {
          s[i][j] = __builtin_amdgcn_mfma_f32_16x16x32_bf16(kf0, qf[i][0], s[i][j], 0, 0, 0);
          s[i][j] = __builtin_amdgcn_mfma_f32_16x16x32_bf16(kf1, qf[i][1], s[i][j], 0, 0, 0);
        }
      }
      if (kt == qt) {
        for (int i = 0; i < 2; ++i) {
          int qg = q0 + wave * 32 + i * 16 + col;
          for (int j = 0; j < 8; ++j) {
            int kg = k0 + j * 16 + quad * 4;
            for (int r = 0; r < 4; ++r)
              if (kg + r > qg) s[i][j][r] = -3.0e38f;
          }
        }
      }
      for (int i = 0; i < 2; ++i) {
        f32x4 vm = s[i][0];
        for (int j = 1; j < 8; ++j)
          for (int r = 0; r < 4; ++r) vm[r] = fmaxf(vm[r], s[i][j][r]);
        float rm = fmaxf(fmaxf(vm[0], vm[1]), fmaxf(vm[2], vm[3]));
        rm = fmaxf(rm, __shfl_xor(rm, 16));
        rm = fmaxf(rm, __shfl_xor(rm, 32));
        float mnew = fmaxf(mst[i], rm);
        float alpha = __builtin_amdgcn_exp2f(mst[i] - mnew);
        mst[i] = mnew;
        float rs = 0.f;
        for (int j = 0; j < 8; ++j)
          for (int r = 0; r < 4; ++r) {
            float p = __builtin_amdgcn_exp2f(s[i][j][r] - mnew);
            s[i][j][r] = p;
            rs += p;
          }
        rs += __shfl_xor(rs, 16);
        rs += __shfl_xor(rs, 32);
        lst[i] = lst[i] * alpha + rs;
        for (int dt = 0; dt < 4; ++dt)
          for (int r = 0; r < 4; ++r) oacc[i][dt][r] *= alpha;
      }
      for (int p2 = 0; p2 < 4; ++p2) {
        short8 pf[2];
        for (int i = 0; i < 2; ++i) {
          uint4v w;
          w[0] = pk2(s[i][2 * p2][1], s[i][2 * p2][0]);
          w[1] = pk2(s[i][2 * p2][3], s[i][2 * p2][2]);
          w[2] = pk2(s[i][2 * p2 + 1][1], s[i][2 * p2 + 1][0]);
          w[3] = pk2(s[i][2 * p2 + 1][3], s[i][2 * p2 + 1][2]);
          pf[i] = *(short8*)&w;
        }
        for (int dt = 0; dt < 4; ++dt) {
          short8 vf = *(const short8*)(lds + VS_OFF + (dt * 16 + col) * 136 + p2 * 32 + quad * 8);
          for (int i = 0; i < 2; ++i)
            oacc[i][dt] = __builtin_amdgcn_mfma_f32_16x16x32_bf16(vf, pf[i], oacc[i][dt], 0, 0, 0);
        }
      }
    }
    for (int i = 0; i < 2; ++i) {
      float linv = 1.0f / lst[i];
      int t = q0 + wave * 32 + i * 16 + col;
      size_t base = ((size_t)(b * 2048 + t)) * 1024 + h * 64;
      for (int dt = 0; dt < 4; ++dt) {
        ushort4 pk;
        pk.x = f2bf(oacc[i][dt][0] * linv);
        pk.y = f2bf(oacc[i][dt][1] * linv);
        pk.z = f2bf(oacc[i][dt][2] * linv);
        pk.w = f2bf(oacc[i][dt][3] * linv);
        *(ushort4*)(Yb + base + dt * 16 + quad * 4) = pk;
      }
    }
  }
}

extern "C" void kernel_launch(void* const* d_in, const int* in_sizes, int n_in,
                              void* d_out, int out_size, void* d_ws, size_t ws_size,
                              hipStream_t stream) {
  const float* x     = (const float*)d_in[0];
  const float* qkv_w = (const float*)d_in[1];
  const float* qkv_b = (const float*)d_in[2];
  const float* o_w   = (const float*)d_in[3];
  const float* o_b   = (const float*)d_in[4];
  float* out = (float*)d_out;
  char* ws = (char*)d_ws;
  ushort_t* Xb  = (ushort_t*)(ws);              // 16 MB (aliased as Yb later)
  ushort_t* W1t = (ushort_t*)(ws + 16777216);   // 6 MB  [3072][1024]
  ushort_t* W2t = (ushort_t*)(ws + 23068672);   // 2 MB  [1024][1024]
  ushort_t* Qb  = (ushort_t*)(ws + 25165824);   // 16 MB [64][2048][64] (pre-scaled)
  ushort_t* Kb  = (ushort_t*)(ws + 41943040);   // 16 MB
  ushort_t* Vtb = (ushort_t*)(ws + 58720256);   // 16 MB [64][64][2048]
  ushort_t* Yb  = Xb;                           // alias: X dead after gemm_qkv

  cvt_f32_to_bf16_vec<<<4096, 256, 0, stream>>>(x, Xb, 1048576);
  transpose_to_bf16<<<dim3(48, 16), 256, 0, stream>>>(qkv_w, W1t, 1024, 3072);
  transpose_to_bf16<<<dim3(16, 16), 256, 0, stream>>>(o_w, W2t, 1024, 1024);
  gemm_qkv<<<768, 256, 0, stream>>>(Xb, W1t, qkv_b, Qb, Kb, Vtb);
  attn<<<512, 256, 0, stream>>>(Qb, Kb, Vtb, Yb);
  gemm_out_k<<<512, 256, 0, stream>>>(Yb, W2t, o_b, out);
}

// Round 5
// 253.678 us; speedup vs baseline: 1.9072x; 1.9072x over previous
//
#include <hip/hip_runtime.h>

typedef unsigned short ushort_t;
typedef __attribute__((ext_vector_type(8))) short short8;
typedef __attribute__((ext_vector_type(4))) float f32x4;
typedef __attribute__((ext_vector_type(4))) unsigned int uint4v;

__device__ __forceinline__ ushort_t f2bf(float f) {
  union { float f; unsigned int u; } v; v.f = f;
  unsigned int u = v.u;
  unsigned int r = (u + 0x7fffu + ((u >> 16) & 1u)) >> 16;
  return (ushort_t)r;
}

// pack two f32 -> dword of two truncated bf16 (lo from 'lo', hi from 'hi')
__device__ __forceinline__ unsigned int pk2(float hi, float lo) {
  union { float f; unsigned int u; } a, b; a.f = lo; b.f = hi;
  return __builtin_amdgcn_perm(b.u, a.u, 0x07060302u);
}

__device__ __forceinline__ void load_lds16(const void* g, void* l) {
  __builtin_amdgcn_global_load_lds(
      (const __attribute__((address_space(1))) unsigned int*)g,
      (__attribute__((address_space(3))) unsigned int*)l, 16, 0, 0);
}

// ---------------- fused prep: x->bf16 cvt + both weight transposes ----------
// blocks [0,4096): cvt x (f32->bf16, 8 elems/thread)
// blocks [4096,4864): transpose qkv_w [1024][3072] -> W1t [3072][1024] bf16
// blocks [4864,5120): transpose o_w [1024][1024] -> W2t [1024][1024] bf16
__global__ __launch_bounds__(256) void prep(
    const float* __restrict__ x, ushort_t* __restrict__ Xb,
    const float* __restrict__ qkv_w, ushort_t* __restrict__ W1t,
    const float* __restrict__ o_w, ushort_t* __restrict__ W2t) {
  __shared__ float tile[64][65];
  const int blk = blockIdx.x;
  const int tid = threadIdx.x;
  if (blk < 4096) {
    int i = blk * 256 + tid;
    const float4* p = (const float4*)x;
    float4 a = p[2 * i];
    float4 b = p[2 * i + 1];
    short8 v;
    v[0] = (short)f2bf(a.x); v[1] = (short)f2bf(a.y);
    v[2] = (short)f2bf(a.z); v[3] = (short)f2bf(a.w);
    v[4] = (short)f2bf(b.x); v[5] = (short)f2bf(b.y);
    v[6] = (short)f2bf(b.z); v[7] = (short)f2bf(b.w);
    *(short8*)(Xb + (size_t)i * 8) = v;
    return;
  }
  const float* in;
  ushort_t* out;
  int R = 1024, C, c0, r0;
  if (blk < 4864) {
    int bx = blk - 4096;  // 48 x 16
    in = qkv_w; out = W1t; C = 3072;
    c0 = (bx % 48) * 64; r0 = (bx / 48) * 64;
  } else {
    int bx = blk - 4864;  // 16 x 16
    in = o_w; out = W2t; C = 1024;
    c0 = (bx % 16) * 64; r0 = (bx / 16) * 64;
  }
  for (int it = 0; it < 16; ++it) {
    int l = it * 256 + tid;
    int r = l >> 6, c = l & 63;
    tile[r][c] = in[(size_t)(r0 + r) * C + c0 + c];
  }
  __syncthreads();
  for (int it = 0; it < 16; ++it) {
    int l = it * 256 + tid;
    int ro = l >> 6, co = l & 63;
    out[(size_t)(c0 + ro) * R + r0 + co] = f2bf(tile[co][ro]);
  }
}

// ---------------- m97-style gemm_bt core: C[128x128] = A[M][K] * Bt[N][K]^T ----
// Per-wave 64x64 (acc[4][4]): register sweet spot — 64x128/wave spills (R4).
__device__ __forceinline__ void gemm_bt_main(
    const ushort_t* __restrict__ A, const ushort_t* __restrict__ Bt,
    int K, int bm, int bn, ushort_t* lds, f32x4 acc[4][4]) {
  const int tid = threadIdx.x;
  const int wave = tid >> 6, lane = tid & 63;
  const int quad = lane >> 4, col = lane & 15;
  const int wm = (wave & 1) * 64, wn = (wave >> 1) * 64;
  ushort_t* ldsA = lds;
  ushort_t* ldsB = lds + 8192;
  f32x4 z = {0.f, 0.f, 0.f, 0.f};
  for (int i = 0; i < 4; ++i)
    for (int j = 0; j < 4; ++j) acc[i][j] = z;
  for (int bk = 0; bk < K; bk += 64) {
    for (int is = 0; is < 4; ++is) {
      int o = is * 4096 + wave * 1024 + lane * 16;  // byte offset in 16KB tile
      int p = o >> 13;
      int w = o & 8191;
      int r = w >> 6, kk = (w & 63) >> 1;
      int ldso = (is * 4096 + wave * 1024) >> 1;  // uniform elem offset
      const ushort_t* ga = A + (size_t)(bm + r) * K + bk + p * 32 + kk;
      load_lds16(ga, ldsA + ldso);
      const ushort_t* gb = Bt + (size_t)(bn + r) * K + bk + p * 32 + kk;
      load_lds16(gb, ldsB + ldso);
    }
    __syncthreads();
    for (int ks = 0; ks < 2; ++ks) {
      short8 af[4], bfr[4];
      for (int i = 0; i < 4; ++i)
        af[i] = *(const short8*)(ldsA + ks * 4096 + (wm + i * 16 + col) * 32 + quad * 8);
      for (int j = 0; j < 4; ++j)
        bfr[j] = *(const short8*)(ldsB + ks * 4096 + (wn + j * 16 + col) * 32 + quad * 8);
      for (int i = 0; i < 4; ++i)
        for (int j = 0; j < 4; ++j)
          acc[i][j] = __builtin_amdgcn_mfma_f32_16x16x32_bf16(af[i], bfr[j], acc[i][j], 0, 0, 0);
    }
    __syncthreads();
  }
}

// ---------------- GEMM1: X*W1t^T + b -> Q(scaled) [bh][t][64], K [bh][t][64], Vt [bh][64][t]
// Q pre-scaled by 0.125*log2(e) for exp2-domain softmax.
__global__ __launch_bounds__(256) void gemm_qkv(
    const ushort_t* __restrict__ Xb, const ushort_t* __restrict__ W1t,
    const float* __restrict__ bias, ushort_t* __restrict__ Qb,
    ushort_t* __restrict__ Kb, ushort_t* __restrict__ Vtb) {
  __shared__ ushort_t lds[16384];
  const int ntile = 3072 / 128;
  int bn = (blockIdx.x % ntile) * 128;
  int bm = (blockIdx.x / ntile) * 128;
  f32x4 acc[4][4];
  gemm_bt_main(Xb, W1t, 1024, bm, bn, lds, acc);
  const int tid = threadIdx.x, wave = tid >> 6, lane = tid & 63;
  const int quad = lane >> 4, col = lane & 15;
  const int wm = (wave & 1) * 64, wn = (wave >> 1) * 64;
  const float SCL = 0.18033688011112042f;  // 0.125 * log2(e)
  int which = bn >> 10;  // 0=q, 1=k, 2=v (uniform per block)
  for (int i = 0; i < 4; ++i) {
    int row0 = bm + wm + i * 16 + quad * 4;
    int b = row0 >> 11, t0 = row0 & 2047;
    for (int j = 0; j < 4; ++j) {
      int cg = bn + wn + j * 16 + col;
      float bv = bias[cg];
      int rem = cg & 1023;
      int h = rem >> 6, hd = rem & 63;
      size_t bh = (size_t)(b * 16 + h);
      if (which == 0) {
        for (int r = 0; r < 4; ++r)
          Qb[(bh * 2048 + t0 + r) * 64 + hd] = f2bf((acc[i][j][r] + bv) * SCL);
      } else if (which == 1) {
        for (int r = 0; r < 4; ++r)
          Kb[(bh * 2048 + t0 + r) * 64 + hd] = f2bf(acc[i][j][r] + bv);
      } else {
        ushort4 pk;
        pk.x = f2bf(acc[i][j][0] + bv);
        pk.y = f2bf(acc[i][j][1] + bv);
        pk.z = f2bf(acc[i][j][2] + bv);
        pk.w = f2bf(acc[i][j][3] + bv);
        *(ushort4*)(Vtb + (bh * 64 + hd) * 2048 + t0) = pk;
      }
    }
  }
}

// ---------------- GEMM2: Y*W2t^T + b -> out (fp32) ----------------
__global__ __launch_bounds__(256) void gemm_out_k(
    const ushort_t* __restrict__ Yb, const ushort_t* __restrict__ W2t,
    const float* __restrict__ bias, float* __restrict__ out) {
  __shared__ ushort_t lds[16384];
  const int ntile = 1024 / 128;
  int bn = (blockIdx.x % ntile) * 128;
  int bm = (blockIdx.x / ntile) * 128;
  f32x4 acc[4][4];
  gemm_bt_main(Yb, W2t, 1024, bm, bn, lds, acc);
  const int tid = threadIdx.x, wave = tid >> 6, lane = tid & 63;
  const int quad = lane >> 4, col = lane & 15;
  const int wm = (wave & 1) * 64, wn = (wave >> 1) * 64;
  for (int i = 0; i < 4; ++i) {
    int row0 = bm + wm + i * 16 + quad * 4;
    for (int j = 0; j < 4; ++j) {
      int cg = bn + wn + j * 16 + col;
      float bv = bias[cg];
      for (int r = 0; r < 4; ++r)
        out[(size_t)(row0 + r) * 1024 + cg] = acc[i][j][r] + bv;
    }
  }
}

// ---------------- flash attention, transposed-S, balanced persistent ----------
// Q(pre-scaled),K: [bh][2048][64] bf16; Vt: [bh][64][2048] bf16; Y: [b][t][1024].
// 512 blocks; block (a=blk>>6, bh=blk&63) processes q-tile 15-a then q-tile a
// => exactly 17 k-tiles per block (perfect balance, all resident).
// K/V tile kt+1 prefetched into registers during compute of kt.
// S^T = K*Q^T; P^T feeds PV as B-operand via permuted-k contraction;
// V staged into LDS pre-permuted (verified R2/R3).
#define KS_OFF 0      // K tile [128][72] elems
#define VS_OFF 9216   // V tile [64][136] elems, k-permuted within 32-groups
__global__ __launch_bounds__(256, 2) void attn(
    const ushort_t* __restrict__ Qb, const ushort_t* __restrict__ Kb,
    const ushort_t* __restrict__ Vtb, ushort_t* __restrict__ Yb) {
  __shared__ ushort_t lds[17920];  // 35840 B
  const int tid = threadIdx.x, wave = tid >> 6, lane = tid & 63;
  const int quad = lane >> 4, col = lane & 15;
  const int bh = blockIdx.x & 63;
  const int a = blockIdx.x >> 6;  // 0..7
  const int b = bh >> 4, h = bh & 15;
  const ushort_t* Qg = Qb + (size_t)bh * 2048 * 64;
  const ushort_t* Kg = Kb + (size_t)bh * 2048 * 64;
  const ushort_t* Vg = Vtb + (size_t)bh * 64 * 2048;
  const int kv = tid;
  f32x4 z = {0.f, 0.f, 0.f, 0.f};

  for (int item = 0; item < 2; ++item) {
    const int qt = item == 0 ? 15 - a : a;
    const int q0 = qt * 128;
    short8 qf[2][2];
    for (int i = 0; i < 2; ++i)
      for (int ks = 0; ks < 2; ++ks)
        qf[i][ks] = *(const short8*)(
            Qg + (size_t)(q0 + wave * 32 + i * 16 + col) * 64 + ks * 32 + quad * 8);
    short8 kpre[4], vpre[4];
#pragma unroll
    for (int it = 0; it < 4; ++it) {
      int v = it * 256 + kv;
      kpre[it] = *(const short8*)(Kg + (size_t)(0 + (v >> 3)) * 64 + (v & 7) * 8);
      vpre[it] = *(const short8*)(Vg + (size_t)(v >> 4) * 2048 + 0 + (v & 15) * 8);
    }

    f32x4 oacc[2][4];
    float mst[2] = {-3.0e38f, -3.0e38f}, lst[2] = {0.f, 0.f};
    for (int i = 0; i < 2; ++i)
      for (int dt = 0; dt < 4; ++dt) oacc[i][dt] = z;

    for (int kt = 0; kt <= qt; ++kt) {
      int k0 = kt * 128;
      __syncthreads();
#pragma unroll
      for (int it = 0; it < 4; ++it) {
        int v = it * 256 + kv;
        *(short8*)(lds + KS_OFF + (v >> 3) * 72 + (v & 7) * 8) = kpre[it];
      }
#pragma unroll
      for (int it = 0; it < 4; ++it) {
        int v = it * 256 + kv;
        int d = v >> 4, kc = (v & 15) * 8;
        int p = kc >> 5, u = (kc >> 4) & 1, g0 = (kc >> 2) & 3;
        int pos1 = p * 32 + g0 * 8 + u * 4;
        short8 val = vpre[it];
        ushort4 lo4, hi4;
        lo4.x = (ushort_t)val[0]; lo4.y = (ushort_t)val[1];
        lo4.z = (ushort_t)val[2]; lo4.w = (ushort_t)val[3];
        hi4.x = (ushort_t)val[4]; hi4.y = (ushort_t)val[5];
        hi4.z = (ushort_t)val[6]; hi4.w = (ushort_t)val[7];
        *(ushort4*)(lds + VS_OFF + d * 136 + pos1) = lo4;
        *(ushort4*)(lds + VS_OFF + d * 136 + pos1 + 8) = hi4;
      }
      __syncthreads();
      if (kt < qt) {
        int k0n = k0 + 128;
#pragma unroll
        for (int it = 0; it < 4; ++it) {
          int v = it * 256 + kv;
          kpre[it] = *(const short8*)(Kg + (size_t)(k0n + (v >> 3)) * 64 + (v & 7) * 8);
          vpre[it] = *(const short8*)(Vg + (size_t)(v >> 4) * 2048 + k0n + (v & 15) * 8);
        }
      }
      f32x4 s[2][8];
      for (int i = 0; i < 2; ++i)
        for (int j = 0; j < 8; ++j) s[i][j] = z;
      for (int j = 0; j < 8; ++j) {
        short8 kf0 = *(const short8*)(lds + KS_OFF + (j * 16 + col) * 72 + quad * 8);
        short8 kf1 = *(const short8*)(lds + KS_OFF + (j * 16 + col) * 72 + 32 + quad * 8);
        for (int i = 0; i < 2; ++i) {
          s[i][j] = __builtin_amdgcn_mfma_f32_16x16x32_bf16(kf0, qf[i][0], s[i][j], 0, 0, 0);
          s[i][j] = __builtin_amdgcn_mfma_f32_16x16x32_bf16(kf1, qf[i][1], s[i][j], 0, 0, 0);
        }
      }
      if (kt == qt) {
        for (int i = 0; i < 2; ++i) {
          int qg = q0 + wave * 32 + i * 16 + col;
          for (int j = 0; j < 8; ++j) {
            int kg = k0 + j * 16 + quad * 4;
            for (int r = 0; r < 4; ++r)
              if (kg + r > qg) s[i][j][r] = -3.0e38f;
          }
        }
      }
      for (int i = 0; i < 2; ++i) {
        f32x4 vm = s[i][0];
        for (int j = 1; j < 8; ++j)
          for (int r = 0; r < 4; ++r) vm[r] = fmaxf(vm[r], s[i][j][r]);
        float rm = fmaxf(fmaxf(vm[0], vm[1]), fmaxf(vm[2], vm[3]));
        rm = fmaxf(rm, __shfl_xor(rm, 16));
        rm = fmaxf(rm, __shfl_xor(rm, 32));
        float mnew = fmaxf(mst[i], rm);
        float alpha = __builtin_amdgcn_exp2f(mst[i] - mnew);
        mst[i] = mnew;
        float rs = 0.f;
        for (int j = 0; j < 8; ++j)
          for (int r = 0; r < 4; ++r) {
            float p = __builtin_amdgcn_exp2f(s[i][j][r] - mnew);
            s[i][j][r] = p;
            rs += p;
          }
        rs += __shfl_xor(rs, 16);
        rs += __shfl_xor(rs, 32);
        lst[i] = lst[i] * alpha + rs;
        for (int dt = 0; dt < 4; ++dt)
          for (int r = 0; r < 4; ++r) oacc[i][dt][r] *= alpha;
      }
      for (int p2 = 0; p2 < 4; ++p2) {
        short8 pf[2];
        for (int i = 0; i < 2; ++i) {
          uint4v w;
          w[0] = pk2(s[i][2 * p2][1], s[i][2 * p2][0]);
          w[1] = pk2(s[i][2 * p2][3], s[i][2 * p2][2]);
          w[2] = pk2(s[i][2 * p2 + 1][1], s[i][2 * p2 + 1][0]);
          w[3] = pk2(s[i][2 * p2 + 1][3], s[i][2 * p2 + 1][2]);
          pf[i] = *(short8*)&w;
        }
        for (int dt = 0; dt < 4; ++dt) {
          short8 vf = *(const short8*)(lds + VS_OFF + (dt * 16 + col) * 136 + p2 * 32 + quad * 8);
          for (int i = 0; i < 2; ++i)
            oacc[i][dt] = __builtin_amdgcn_mfma_f32_16x16x32_bf16(vf, pf[i], oacc[i][dt], 0, 0, 0);
        }
      }
    }
    for (int i = 0; i < 2; ++i) {
      float linv = 1.0f / lst[i];
      int t = q0 + wave * 32 + i * 16 + col;
      size_t base = ((size_t)(b * 2048 + t)) * 1024 + h * 64;
      for (int dt = 0; dt < 4; ++dt) {
        ushort4 pk;
        pk.x = f2bf(oacc[i][dt][0] * linv);
        pk.y = f2bf(oacc[i][dt][1] * linv);
        pk.z = f2bf(oacc[i][dt][2] * linv);
        pk.w = f2bf(oacc[i][dt][3] * linv);
        *(ushort4*)(Yb + base + dt * 16 + quad * 4) = pk;
      }
    }
  }
}

extern "C" void kernel_launch(void* const* d_in, const int* in_sizes, int n_in,
                              void* d_out, int out_size, void* d_ws, size_t ws_size,
                              hipStream_t stream) {
  const float* x     = (const float*)d_in[0];
  const float* qkv_w = (const float*)d_in[1];
  const float* qkv_b = (const float*)d_in[2];
  const float* o_w   = (const float*)d_in[3];
  const float* o_b   = (const float*)d_in[4];
  float* out = (float*)d_out;
  char* ws = (char*)d_ws;
  ushort_t* Xb  = (ushort_t*)(ws);              // 16 MB (aliased as Yb later)
  ushort_t* W1t = (ushort_t*)(ws + 16777216);   // 6 MB  [3072][1024]
  ushort_t* W2t = (ushort_t*)(ws + 23068672);   // 2 MB  [1024][1024]
  ushort_t* Qb  = (ushort_t*)(ws + 25165824);   // 16 MB [64][2048][64] (pre-scaled)
  ushort_t* Kb  = (ushort_t*)(ws + 41943040);   // 16 MB
  ushort_t* Vtb = (ushort_t*)(ws + 58720256);   // 16 MB [64][64][2048]
  ushort_t* Yb  = Xb;                           // alias: X dead after gemm_qkv

  prep<<<5120, 256, 0, stream>>>(x, Xb, qkv_w, W1t, o_w, W2t);
  gemm_qkv<<<1536, 256, 0, stream>>>(Xb, W1t, qkv_b, Qb, Kb, Vtb);
  attn<<<512, 256, 0, stream>>>(Qb, Kb, Vtb, Yb);
  gemm_out_k<<<512, 256, 0, stream>>>(Yb, W2t, o_b, out);
}

// Round 6
// 245.042 us; speedup vs baseline: 1.9744x; 1.0352x over previous
//
#include <hip/hip_runtime.h>

typedef unsigned short ushort_t;
typedef __attribute__((ext_vector_type(8))) short short8;
typedef __attribute__((ext_vector_type(4))) float f32x4;
typedef __attribute__((ext_vector_type(4))) unsigned int uint4v;

__device__ __forceinline__ ushort_t f2bf(float f) {
  union { float f; unsigned int u; } v; v.f = f;
  unsigned int u = v.u;
  unsigned int r = (u + 0x7fffu + ((u >> 16) & 1u)) >> 16;
  return (ushort_t)r;
}

// pack two f32 -> dword of two truncated bf16 (lo from 'lo', hi from 'hi')
__device__ __forceinline__ unsigned int pk2(float hi, float lo) {
  union { float f; unsigned int u; } a, b; a.f = lo; b.f = hi;
  return __builtin_amdgcn_perm(b.u, a.u, 0x07060302u);
}

__device__ __forceinline__ void load_lds16(const void* g, void* l) {
  __builtin_amdgcn_global_load_lds(
      (const __attribute__((address_space(1))) unsigned int*)g,
      (__attribute__((address_space(3))) unsigned int*)l, 16, 0, 0);
}

// ---------------- fused prep: x->bf16 cvt + both weight transposes ----------
__global__ __launch_bounds__(256) void prep(
    const float* __restrict__ x, ushort_t* __restrict__ Xb,
    const float* __restrict__ qkv_w, ushort_t* __restrict__ W1t,
    const float* __restrict__ o_w, ushort_t* __restrict__ W2t) {
  __shared__ float tile[64][65];
  const int blk = blockIdx.x;
  const int tid = threadIdx.x;
  if (blk < 4096) {
    int i = blk * 256 + tid;
    const float4* p = (const float4*)x;
    float4 a = p[2 * i];
    float4 b = p[2 * i + 1];
    short8 v;
    v[0] = (short)f2bf(a.x); v[1] = (short)f2bf(a.y);
    v[2] = (short)f2bf(a.z); v[3] = (short)f2bf(a.w);
    v[4] = (short)f2bf(b.x); v[5] = (short)f2bf(b.y);
    v[6] = (short)f2bf(b.z); v[7] = (short)f2bf(b.w);
    *(short8*)(Xb + (size_t)i * 8) = v;
    return;
  }
  const float* in;
  ushort_t* out;
  int R = 1024, C, c0, r0;
  if (blk < 4864) {
    int bx = blk - 4096;  // 48 x 16
    in = qkv_w; out = W1t; C = 3072;
    c0 = (bx % 48) * 64; r0 = (bx / 48) * 64;
  } else {
    int bx = blk - 4864;  // 16 x 16
    in = o_w; out = W2t; C = 1024;
    c0 = (bx % 16) * 64; r0 = (bx / 16) * 64;
  }
  for (int it = 0; it < 16; ++it) {
    int l = it * 256 + tid;
    int r = l >> 6, c = l & 63;
    tile[r][c] = in[(size_t)(r0 + r) * C + c0 + c];
  }
  __syncthreads();
  for (int it = 0; it < 16; ++it) {
    int l = it * 256 + tid;
    int ro = l >> 6, co = l & 63;
    out[(size_t)(c0 + ro) * R + r0 + co] = f2bf(tile[co][ro]);
  }
}

// ---------------- m97-style gemm_bt core: C[128x128] = A[M][K] * Bt[N][K]^T ----
// Per-wave 64x64 (acc[4][4]): register sweet spot — 64x128/wave spills (R4).
__device__ __forceinline__ void gemm_bt_main(
    const ushort_t* __restrict__ A, const ushort_t* __restrict__ Bt,
    int K, int bm, int bn, ushort_t* lds, f32x4 acc[4][4]) {
  const int tid = threadIdx.x;
  const int wave = tid >> 6, lane = tid & 63;
  const int quad = lane >> 4, col = lane & 15;
  const int wm = (wave & 1) * 64, wn = (wave >> 1) * 64;
  ushort_t* ldsA = lds;
  ushort_t* ldsB = lds + 8192;
  f32x4 z = {0.f, 0.f, 0.f, 0.f};
  for (int i = 0; i < 4; ++i)
    for (int j = 0; j < 4; ++j) acc[i][j] = z;
  for (int bk = 0; bk < K; bk += 64) {
    for (int is = 0; is < 4; ++is) {
      int o = is * 4096 + wave * 1024 + lane * 16;  // byte offset in 16KB tile
      int p = o >> 13;
      int w = o & 8191;
      int r = w >> 6, kk = (w & 63) >> 1;
      int ldso = (is * 4096 + wave * 1024) >> 1;  // uniform elem offset
      const ushort_t* ga = A + (size_t)(bm + r) * K + bk + p * 32 + kk;
      load_lds16(ga, ldsA + ldso);
      const ushort_t* gb = Bt + (size_t)(bn + r) * K + bk + p * 32 + kk;
      load_lds16(gb, ldsB + ldso);
    }
    __syncthreads();
    for (int ks = 0; ks < 2; ++ks) {
      short8 af[4], bfr[4];
      for (int i = 0; i < 4; ++i)
        af[i] = *(const short8*)(ldsA + ks * 4096 + (wm + i * 16 + col) * 32 + quad * 8);
      for (int j = 0; j < 4; ++j)
        bfr[j] = *(const short8*)(ldsB + ks * 4096 + (wn + j * 16 + col) * 32 + quad * 8);
      for (int i = 0; i < 4; ++i)
        for (int j = 0; j < 4; ++j)
          acc[i][j] = __builtin_amdgcn_mfma_f32_16x16x32_bf16(af[i], bfr[j], acc[i][j], 0, 0, 0);
    }
    __syncthreads();
  }
}

// ---------------- GEMM1: X*W1t^T + b, 256x128 tile, 512 threads (8 waves x 64x64)
// -> Q(scaled) [bh][t][64], K [bh][t][64], Vt [bh][64][t]
// Q pre-scaled by 0.125*log2(e) for exp2-domain softmax.
// Per-wave acc stays [4][4] (64 VGPR) — the R4 spill came from 128/lane.
__global__ __launch_bounds__(512, 4) void gemm_qkv(
    const ushort_t* __restrict__ Xb, const ushort_t* __restrict__ W1t,
    const float* __restrict__ bias, ushort_t* __restrict__ Qb,
    ushort_t* __restrict__ Kb, ushort_t* __restrict__ Vtb) {
  __shared__ ushort_t lds[24576];  // A [2][256][32] = 16384 el + B [2][128][32] = 8192 el
  const int K = 1024;
  const int bn = (blockIdx.x % 24) * 128;
  const int bm = (blockIdx.x / 24) * 256;
  const int tid = threadIdx.x;
  const int wave = tid >> 6, lane = tid & 63;
  const int quad = lane >> 4, col = lane & 15;
  const int wm = (wave & 3) * 64;    // 4 m-slices of 64
  const int wn = (wave >> 2) * 64;   // 2 n-slices of 64
  ushort_t* ldsA = lds;
  ushort_t* ldsB = lds + 16384;
  f32x4 z = {0.f, 0.f, 0.f, 0.f};
  f32x4 acc[4][4];
  for (int i = 0; i < 4; ++i)
    for (int j = 0; j < 4; ++j) acc[i][j] = z;

  for (int bk = 0; bk < K; bk += 64) {
    // A tile: 256 rows x 64 k -> planes [2][256][32]; 4 x 512 x 16B = 32 KB
#pragma unroll
    for (int is = 0; is < 4; ++is) {
      int o = is * 8192 + wave * 1024 + lane * 16;
      int p = o >> 14, w = o & 16383;
      int r = w >> 6, kk = (w & 63) >> 1;
      int ldso = (is * 8192 + wave * 1024) >> 1;
      load_lds16(Xb + (size_t)(bm + r) * K + bk + p * 32 + kk, ldsA + ldso);
    }
    // B tile: 128 rows x 64 k -> planes [2][128][32]; 2 x 512 x 16B = 16 KB
#pragma unroll
    for (int is = 0; is < 2; ++is) {
      int o = is * 8192 + wave * 1024 + lane * 16;
      int p = o >> 13, w = o & 8191;
      int r = w >> 6, kk = (w & 63) >> 1;
      int ldso = (is * 8192 + wave * 1024) >> 1;
      load_lds16(W1t + (size_t)(bn + r) * K + bk + p * 32 + kk, ldsB + ldso);
    }
    __syncthreads();
#pragma unroll
    for (int ks = 0; ks < 2; ++ks) {
      short8 af[4], bfr[4];
      for (int i = 0; i < 4; ++i)
        af[i] = *(const short8*)(ldsA + ks * 8192 + (wm + i * 16 + col) * 32 + quad * 8);
      for (int j = 0; j < 4; ++j)
        bfr[j] = *(const short8*)(ldsB + ks * 4096 + (wn + j * 16 + col) * 32 + quad * 8);
      for (int i = 0; i < 4; ++i)
        for (int j = 0; j < 4; ++j)
          acc[i][j] = __builtin_amdgcn_mfma_f32_16x16x32_bf16(af[i], bfr[j], acc[i][j], 0, 0, 0);
    }
    __syncthreads();
  }

  const float SCL = 0.18033688011112042f;  // 0.125 * log2(e)
  const int which = bn >> 10;  // 0=q, 1=k, 2=v (uniform per block)
  for (int i = 0; i < 4; ++i) {
    int row0 = bm + wm + i * 16 + quad * 4;
    int b = row0 >> 11, t0 = row0 & 2047;
    for (int j = 0; j < 4; ++j) {
      int cg = bn + wn + j * 16 + col;
      float bv = bias[cg];
      int rem = cg & 1023;
      int h = rem >> 6, hd = rem & 63;
      size_t bh = (size_t)(b * 16 + h);
      if (which == 0) {
        for (int r = 0; r < 4; ++r)
          Qb[(bh * 2048 + t0 + r) * 64 + hd] = f2bf((acc[i][j][r] + bv) * SCL);
      } else if (which == 1) {
        for (int r = 0; r < 4; ++r)
          Kb[(bh * 2048 + t0 + r) * 64 + hd] = f2bf(acc[i][j][r] + bv);
      } else {
        ushort4 pk;
        pk.x = f2bf(acc[i][j][0] + bv);
        pk.y = f2bf(acc[i][j][1] + bv);
        pk.z = f2bf(acc[i][j][2] + bv);
        pk.w = f2bf(acc[i][j][3] + bv);
        *(ushort4*)(Vtb + (bh * 64 + hd) * 2048 + t0) = pk;
      }
    }
  }
}

// ---------------- GEMM2: Y*W2t^T + b -> out (fp32) ----------------
__global__ __launch_bounds__(256) void gemm_out_k(
    const ushort_t* __restrict__ Yb, const ushort_t* __restrict__ W2t,
    const float* __restrict__ bias, float* __restrict__ out) {
  __shared__ ushort_t lds[16384];
  const int ntile = 1024 / 128;
  int bn = (blockIdx.x % ntile) * 128;
  int bm = (blockIdx.x / ntile) * 128;
  f32x4 acc[4][4];
  gemm_bt_main(Yb, W2t, 1024, bm, bn, lds, acc);
  const int tid = threadIdx.x, wave = tid >> 6, lane = tid & 63;
  const int quad = lane >> 4, col = lane & 15;
  const int wm = (wave & 1) * 64, wn = (wave >> 1) * 64;
  for (int i = 0; i < 4; ++i) {
    int row0 = bm + wm + i * 16 + quad * 4;
    for (int j = 0; j < 4; ++j) {
      int cg = bn + wn + j * 16 + col;
      float bv = bias[cg];
      for (int r = 0; r < 4; ++r)
        out[(size_t)(row0 + r) * 1024 + cg] = acc[i][j][r] + bv;
    }
  }
}

// ---------------- flash attention, transposed-S, balanced persistent ----------
// (unchanged from R5 — verified; see R2/R3 notes)
#define KS_OFF 0      // K tile [128][72] elems
#define VS_OFF 9216   // V tile [64][136] elems, k-permuted within 32-groups
__global__ __launch_bounds__(256, 2) void attn(
    const ushort_t* __restrict__ Qb, const ushort_t* __restrict__ Kb,
    const ushort_t* __restrict__ Vtb, ushort_t* __restrict__ Yb) {
  __shared__ ushort_t lds[17920];  // 35840 B
  const int tid = threadIdx.x, wave = tid >> 6, lane = tid & 63;
  const int quad = lane >> 4, col = lane & 15;
  const int bh = blockIdx.x & 63;
  const int a = blockIdx.x >> 6;  // 0..7
  const int b = bh >> 4, h = bh & 15;
  const ushort_t* Qg = Qb + (size_t)bh * 2048 * 64;
  const ushort_t* Kg = Kb + (size_t)bh * 2048 * 64;
  const ushort_t* Vg = Vtb + (size_t)bh * 64 * 2048;
  const int kv = tid;
  f32x4 z = {0.f, 0.f, 0.f, 0.f};

  for (int item = 0; item < 2; ++item) {
    const int qt = item == 0 ? 15 - a : a;
    const int q0 = qt * 128;
    short8 qf[2][2];
    for (int i = 0; i < 2; ++i)
      for (int ks = 0; ks < 2; ++ks)
        qf[i][ks] = *(const short8*)(
            Qg + (size_t)(q0 + wave * 32 + i * 16 + col) * 64 + ks * 32 + quad * 8);
    short8 kpre[4], vpre[4];
#pragma unroll
    for (int it = 0; it < 4; ++it) {
      int v = it * 256 + kv;
      kpre[it] = *(const short8*)(Kg + (size_t)(0 + (v >> 3)) * 64 + (v & 7) * 8);
      vpre[it] = *(const short8*)(Vg + (size_t)(v >> 4) * 2048 + 0 + (v & 15) * 8);
    }

    f32x4 oacc[2][4];
    float mst[2] = {-3.0e38f, -3.0e38f}, lst[2] = {0.f, 0.f};
    for (int i = 0; i < 2; ++i)
      for (int dt = 0; dt < 4; ++dt) oacc[i][dt] = z;

    for (int kt = 0; kt <= qt; ++kt) {
      int k0 = kt * 128;
      __syncthreads();
#pragma unroll
      for (int it = 0; it < 4; ++it) {
        int v = it * 256 + kv;
        *(short8*)(lds + KS_OFF + (v >> 3) * 72 + (v & 7) * 8) = kpre[it];
      }
#pragma unroll
      for (int it = 0; it < 4; ++it) {
        int v = it * 256 + kv;
        int d = v >> 4, kc = (v & 15) * 8;
        int p = kc >> 5, u = (kc >> 4) & 1, g0 = (kc >> 2) & 3;
        int pos1 = p * 32 + g0 * 8 + u * 4;
        short8 val = vpre[it];
        ushort4 lo4, hi4;
        lo4.x = (ushort_t)val[0]; lo4.y = (ushort_t)val[1];
        lo4.z = (ushort_t)val[2]; lo4.w = (ushort_t)val[3];
        hi4.x = (ushort_t)val[4]; hi4.y = (ushort_t)val[5];
        hi4.z = (ushort_t)val[6]; hi4.w = (ushort_t)val[7];
        *(ushort4*)(lds + VS_OFF + d * 136 + pos1) = lo4;
        *(ushort4*)(lds + VS_OFF + d * 136 + pos1 + 8) = hi4;
      }
      __syncthreads();
      if (kt < qt) {
        int k0n = k0 + 128;
#pragma unroll
        for (int it = 0; it < 4; ++it) {
          int v = it * 256 + kv;
          kpre[it] = *(const short8*)(Kg + (size_t)(k0n + (v >> 3)) * 64 + (v & 7) * 8);
          vpre[it] = *(const short8*)(Vg + (size_t)(v >> 4) * 2048 + k0n + (v & 15) * 8);
        }
      }
      f32x4 s[2][8];
      for (int i = 0; i < 2; ++i)
        for (int j = 0; j < 8; ++j) s[i][j] = z;
      for (int j = 0; j < 8; ++j) {
        short8 kf0 = *(const short8*)(lds + KS_OFF + (j * 16 + col) * 72 + quad * 8);
        short8 kf1 = *(const short8*)(lds + KS_OFF + (j * 16 + col) * 72 + 32 + quad * 8);
        for (int i = 0; i < 2; ++i) {
          s[i][j] = __builtin_amdgcn_mfma_f32_16x16x32_bf16(kf0, qf[i][0], s[i][j], 0, 0, 0);
          s[i][j] = __builtin_amdgcn_mfma_f32_16x16x32_bf16(kf1, qf[i][1], s[i][j], 0, 0, 0);
        }
      }
      if (kt == qt) {
        for (int i = 0; i < 2; ++i) {
          int qg = q0 + wave * 32 + i * 16 + col;
          for (int j = 0; j < 8; ++j) {
            int kg = k0 + j * 16 + quad * 4;
            for (int r = 0; r < 4; ++r)
              if (kg + r > qg) s[i][j][r] = -3.0e38f;
          }
        }
      }
      for (int i = 0; i < 2; ++i) {
        f32x4 vm = s[i][0];
        for (int j = 1; j < 8; ++j)
          for (int r = 0; r < 4; ++r) vm[r] = fmaxf(vm[r], s[i][j][r]);
        float rm = fmaxf(fmaxf(vm[0], vm[1]), fmaxf(vm[2], vm[3]));
        rm = fmaxf(rm, __shfl_xor(rm, 16));
        rm = fmaxf(rm, __shfl_xor(rm, 32));
        float mnew = fmaxf(mst[i], rm);
        float alpha = __builtin_amdgcn_exp2f(mst[i] - mnew);
        mst[i] = mnew;
        float rs = 0.f;
        for (int j = 0; j < 8; ++j)
          for (int r = 0; r < 4; ++r) {
            float p = __builtin_amdgcn_exp2f(s[i][j][r] - mnew);
            s[i][j][r] = p;
            rs += p;
          }
        rs += __shfl_xor(rs, 16);
        rs += __shfl_xor(rs, 32);
        lst[i] = lst[i] * alpha + rs;
        for (int dt = 0; dt < 4; ++dt)
          for (int r = 0; r < 4; ++r) oacc[i][dt][r] *= alpha;
      }
      for (int p2 = 0; p2 < 4; ++p2) {
        short8 pf[2];
        for (int i = 0; i < 2; ++i) {
          uint4v w;
          w[0] = pk2(s[i][2 * p2][1], s[i][2 * p2][0]);
          w[1] = pk2(s[i][2 * p2][3], s[i][2 * p2][2]);
          w[2] = pk2(s[i][2 * p2 + 1][1], s[i][2 * p2 + 1][0]);
          w[3] = pk2(s[i][2 * p2 + 1][3], s[i][2 * p2 + 1][2]);
          pf[i] = *(short8*)&w;
        }
        for (int dt = 0; dt < 4; ++dt) {
          short8 vf = *(const short8*)(lds + VS_OFF + (dt * 16 + col) * 136 + p2 * 32 + quad * 8);
          for (int i = 0; i < 2; ++i)
            oacc[i][dt] = __builtin_amdgcn_mfma_f32_16x16x32_bf16(vf, pf[i], oacc[i][dt], 0, 0, 0);
        }
      }
    }
    for (int i = 0; i < 2; ++i) {
      float linv = 1.0f / lst[i];
      int t = q0 + wave * 32 + i * 16 + col;
      size_t base = ((size_t)(b * 2048 + t)) * 1024 + h * 64;
      for (int dt = 0; dt < 4; ++dt) {
        ushort4 pk;
        pk.x = f2bf(oacc[i][dt][0] * linv);
        pk.y = f2bf(oacc[i][dt][1] * linv);
        pk.z = f2bf(oacc[i][dt][2] * linv);
        pk.w = f2bf(oacc[i][dt][3] * linv);
        *(ushort4*)(Yb + base + dt * 16 + quad * 4) = pk;
      }
    }
  }
}

extern "C" void kernel_launch(void* const* d_in, const int* in_sizes, int n_in,
                              void* d_out, int out_size, void* d_ws, size_t ws_size,
                              hipStream_t stream) {
  const float* x     = (const float*)d_in[0];
  const float* qkv_w = (const float*)d_in[1];
  const float* qkv_b = (const float*)d_in[2];
  const float* o_w   = (const float*)d_in[3];
  const float* o_b   = (const float*)d_in[4];
  float* out = (float*)d_out;
  char* ws = (char*)d_ws;
  ushort_t* Xb  = (ushort_t*)(ws);              // 16 MB (aliased as Yb later)
  ushort_t* W1t = (ushort_t*)(ws + 16777216);   // 6 MB  [3072][1024]
  ushort_t* W2t = (ushort_t*)(ws + 23068672);   // 2 MB  [1024][1024]
  ushort_t* Qb  = (ushort_t*)(ws + 25165824);   // 16 MB [64][2048][64] (pre-scaled)
  ushort_t* Kb  = (ushort_t*)(ws + 41943040);   // 16 MB
  ushort_t* Vtb = (ushort_t*)(ws + 58720256);   // 16 MB [64][64][2048]
  ushort_t* Yb  = Xb;                           // alias: X dead after gemm_qkv

  prep<<<5120, 256, 0, stream>>>(x, Xb, qkv_w, W1t, o_w, W2t);
  gemm_qkv<<<768, 512, 0, stream>>>(Xb, W1t, qkv_b, Qb, Kb, Vtb);
  attn<<<512, 256, 0, stream>>>(Qb, Kb, Vtb, Yb);
  gemm_out_k<<<512, 256, 0, stream>>>(Yb, W2t, o_b, out);
}

// Round 7
// 235.362 us; speedup vs baseline: 2.0556x; 1.0411x over previous
//
#include <hip/hip_runtime.h>

typedef unsigned short ushort_t;
typedef __attribute__((ext_vector_type(8))) short short8;
typedef __attribute__((ext_vector_type(4))) float f32x4;
typedef __attribute__((ext_vector_type(4))) unsigned int uint4v;

__device__ __forceinline__ ushort_t f2bf(float f) {
  union { float f; unsigned int u; } v; v.f = f;
  unsigned int u = v.u;
  unsigned int r = (u + 0x7fffu + ((u >> 16) & 1u)) >> 16;
  return (ushort_t)r;
}

// pack two f32 -> dword of two truncated bf16 (lo from 'lo', hi from 'hi')
__device__ __forceinline__ unsigned int pk2(float hi, float lo) {
  union { float f; unsigned int u; } a, b; a.f = lo; b.f = hi;
  return __builtin_amdgcn_perm(b.u, a.u, 0x07060302u);
}

__device__ __forceinline__ void load_lds16(const void* g, void* l) {
  __builtin_amdgcn_global_load_lds(
      (const __attribute__((address_space(1))) unsigned int*)g,
      (__attribute__((address_space(3))) unsigned int*)l, 16, 0, 0);
}

// ---------------- fused prep: x->bf16 cvt + both weight transposes ----------
__global__ __launch_bounds__(256) void prep(
    const float* __restrict__ x, ushort_t* __restrict__ Xb,
    const float* __restrict__ qkv_w, ushort_t* __restrict__ W1t,
    const float* __restrict__ o_w, ushort_t* __restrict__ W2t) {
  __shared__ float tile[64][65];
  const int blk = blockIdx.x;
  const int tid = threadIdx.x;
  if (blk < 4096) {
    int i = blk * 256 + tid;
    const float4* p = (const float4*)x;
    float4 a = p[2 * i];
    float4 b = p[2 * i + 1];
    short8 v;
    v[0] = (short)f2bf(a.x); v[1] = (short)f2bf(a.y);
    v[2] = (short)f2bf(a.z); v[3] = (short)f2bf(a.w);
    v[4] = (short)f2bf(b.x); v[5] = (short)f2bf(b.y);
    v[6] = (short)f2bf(b.z); v[7] = (short)f2bf(b.w);
    *(short8*)(Xb + (size_t)i * 8) = v;
    return;
  }
  const float* in;
  ushort_t* out;
  int R = 1024, C, c0, r0;
  if (blk < 4864) {
    int bx = blk - 4096;  // 48 x 16
    in = qkv_w; out = W1t; C = 3072;
    c0 = (bx % 48) * 64; r0 = (bx / 48) * 64;
  } else {
    int bx = blk - 4864;  // 16 x 16
    in = o_w; out = W2t; C = 1024;
    c0 = (bx % 16) * 64; r0 = (bx / 16) * 64;
  }
  for (int it = 0; it < 16; ++it) {
    int l = it * 256 + tid;
    int r = l >> 6, c = l & 63;
    tile[r][c] = in[(size_t)(r0 + r) * C + c0 + c];
  }
  __syncthreads();
  for (int it = 0; it < 16; ++it) {
    int l = it * 256 + tid;
    int ro = l >> 6, co = l & 63;
    out[(size_t)(c0 + ro) * R + r0 + co] = f2bf(tile[co][ro]);
  }
}

// ---------------- m97-style gemm_bt core: C[128x128] = A[M][K] * Bt[N][K]^T ----
// Per-wave 64x64 (acc[4][4]): register sweet spot — 64x128/wave spills (R4).
__device__ __forceinline__ void gemm_bt_main(
    const ushort_t* __restrict__ A, const ushort_t* __restrict__ Bt,
    int K, int bm, int bn, ushort_t* lds, f32x4 acc[4][4]) {
  const int tid = threadIdx.x;
  const int wave = tid >> 6, lane = tid & 63;
  const int quad = lane >> 4, col = lane & 15;
  const int wm = (wave & 1) * 64, wn = (wave >> 1) * 64;
  ushort_t* ldsA = lds;
  ushort_t* ldsB = lds + 8192;
  f32x4 z = {0.f, 0.f, 0.f, 0.f};
  for (int i = 0; i < 4; ++i)
    for (int j = 0; j < 4; ++j) acc[i][j] = z;
  for (int bk = 0; bk < K; bk += 64) {
    for (int is = 0; is < 4; ++is) {
      int o = is * 4096 + wave * 1024 + lane * 16;  // byte offset in 16KB tile
      int p = o >> 13;
      int w = o & 8191;
      int r = w >> 6, kk = (w & 63) >> 1;
      int ldso = (is * 4096 + wave * 1024) >> 1;  // uniform elem offset
      const ushort_t* ga = A + (size_t)(bm + r) * K + bk + p * 32 + kk;
      load_lds16(ga, ldsA + ldso);
      const ushort_t* gb = Bt + (size_t)(bn + r) * K + bk + p * 32 + kk;
      load_lds16(gb, ldsB + ldso);
    }
    __syncthreads();
    for (int ks = 0; ks < 2; ++ks) {
      short8 af[4], bfr[4];
      for (int i = 0; i < 4; ++i)
        af[i] = *(const short8*)(ldsA + ks * 4096 + (wm + i * 16 + col) * 32 + quad * 8);
      for (int j = 0; j < 4; ++j)
        bfr[j] = *(const short8*)(ldsB + ks * 4096 + (wn + j * 16 + col) * 32 + quad * 8);
      for (int i = 0; i < 4; ++i)
        for (int j = 0; j < 4; ++j)
          acc[i][j] = __builtin_amdgcn_mfma_f32_16x16x32_bf16(af[i], bfr[j], acc[i][j], 0, 0, 0);
    }
    __syncthreads();
  }
}

// ---------------- GEMM1: X*W1t^T + b, 256x128 tile, 512 threads (8 waves x 64x64)
// Register-prefetch K-loop: tile bk+1 loads into regs during bk's MFMA section
// (moves the vmcnt(0) barrier drain off the critical path — attn-proven pattern).
// -> Q(scaled) [bh][t][64], K [bh][t][64], Vt [bh][64][t]
__global__ __launch_bounds__(512, 4) void gemm_qkv(
    const ushort_t* __restrict__ Xb, const ushort_t* __restrict__ W1t,
    const float* __restrict__ bias, ushort_t* __restrict__ Qb,
    ushort_t* __restrict__ Kb, ushort_t* __restrict__ Vtb) {
  __shared__ ushort_t lds[24576];  // A [2][256][32] = 16384 el + B [2][128][32] = 8192 el
  const int K = 1024;
  const int bn = (blockIdx.x % 24) * 128;
  const int bm = (blockIdx.x / 24) * 256;
  const int tid = threadIdx.x;
  const int wave = tid >> 6, lane = tid & 63;
  const int quad = lane >> 4, col = lane & 15;
  const int wm = (wave & 3) * 64;    // 4 m-slices of 64
  const int wn = (wave >> 2) * 64;   // 2 n-slices of 64
  ushort_t* ldsA = lds;
  ushort_t* ldsB = lds + 16384;
  f32x4 z = {0.f, 0.f, 0.f, 0.f};
  f32x4 acc[4][4];
  for (int i = 0; i < 4; ++i)
    for (int j = 0; j < 4; ++j) acc[i][j] = z;

  // per-thread global pointers (advance +64 elems per K-iter) and LDS slots
  const ushort_t* aptr[4];
  const ushort_t* bptr[2];
  ushort_t* aslt[4];
  ushort_t* bslt[2];
#pragma unroll
  for (int is = 0; is < 4; ++is) {
    int o = is * 8192 + wave * 1024 + lane * 16;
    int p = o >> 14, w = o & 16383;
    int r = w >> 6, kk = (w & 63) >> 1;
    aptr[is] = Xb + (size_t)(bm + r) * K + p * 32 + kk;
    aslt[is] = ldsA + ((is * 8192 + wave * 1024) >> 1) + lane * 8;
  }
#pragma unroll
  for (int is = 0; is < 2; ++is) {
    int o = is * 8192 + wave * 1024 + lane * 16;
    int p = o >> 13, w = o & 8191;
    int r = w >> 6, kk = (w & 63) >> 1;
    bptr[is] = W1t + (size_t)(bn + r) * K + p * 32 + kk;
    bslt[is] = ldsB + ((is * 8192 + wave * 1024) >> 1) + lane * 8;
  }
  // prologue: prefetch bk=0 into regs
  short8 apre[4], bpre[2];
#pragma unroll
  for (int is = 0; is < 4; ++is) apre[is] = *(const short8*)aptr[is];
#pragma unroll
  for (int is = 0; is < 2; ++is) bpre[is] = *(const short8*)bptr[is];

  for (int bk = 0; bk < K; bk += 64) {
    __syncthreads();  // previous iteration's frag reads complete
#pragma unroll
    for (int is = 0; is < 4; ++is) *(short8*)aslt[is] = apre[is];
#pragma unroll
    for (int is = 0; is < 2; ++is) *(short8*)bslt[is] = bpre[is];
    __syncthreads();
    if (bk + 64 < K) {  // prefetch next tile; overlaps MFMA section below
#pragma unroll
      for (int is = 0; is < 4; ++is) {
        aptr[is] += 64;
        apre[is] = *(const short8*)aptr[is];
      }
#pragma unroll
      for (int is = 0; is < 2; ++is) {
        bptr[is] += 64;
        bpre[is] = *(const short8*)bptr[is];
      }
    }
#pragma unroll
    for (int ks = 0; ks < 2; ++ks) {
      short8 af[4], bfr[4];
      for (int i = 0; i < 4; ++i)
        af[i] = *(const short8*)(ldsA + ks * 8192 + (wm + i * 16 + col) * 32 + quad * 8);
      for (int j = 0; j < 4; ++j)
        bfr[j] = *(const short8*)(ldsB + ks * 4096 + (wn + j * 16 + col) * 32 + quad * 8);
      for (int i = 0; i < 4; ++i)
        for (int j = 0; j < 4; ++j)
          acc[i][j] = __builtin_amdgcn_mfma_f32_16x16x32_bf16(af[i], bfr[j], acc[i][j], 0, 0, 0);
    }
  }

  const float SCL = 0.18033688011112042f;  // 0.125 * log2(e)
  const int which = bn >> 10;  // 0=q, 1=k, 2=v (uniform per block)
  for (int i = 0; i < 4; ++i) {
    int row0 = bm + wm + i * 16 + quad * 4;
    int b = row0 >> 11, t0 = row0 & 2047;
    for (int j = 0; j < 4; ++j) {
      int cg = bn + wn + j * 16 + col;
      float bv = bias[cg];
      int rem = cg & 1023;
      int h = rem >> 6, hd = rem & 63;
      size_t bh = (size_t)(b * 16 + h);
      if (which == 0) {
        for (int r = 0; r < 4; ++r)
          Qb[(bh * 2048 + t0 + r) * 64 + hd] = f2bf((acc[i][j][r] + bv) * SCL);
      } else if (which == 1) {
        for (int r = 0; r < 4; ++r)
          Kb[(bh * 2048 + t0 + r) * 64 + hd] = f2bf(acc[i][j][r] + bv);
      } else {
        ushort4 pk;
        pk.x = f2bf(acc[i][j][0] + bv);
        pk.y = f2bf(acc[i][j][1] + bv);
        pk.z = f2bf(acc[i][j][2] + bv);
        pk.w = f2bf(acc[i][j][3] + bv);
        *(ushort4*)(Vtb + (bh * 64 + hd) * 2048 + t0) = pk;
      }
    }
  }
}

// ---------------- GEMM2: Y*W2t^T + b -> out (fp32) ----------------
__global__ __launch_bounds__(256) void gemm_out_k(
    const ushort_t* __restrict__ Yb, const ushort_t* __restrict__ W2t,
    const float* __restrict__ bias, float* __restrict__ out) {
  __shared__ ushort_t lds[16384];
  const int ntile = 1024 / 128;
  int bn = (blockIdx.x % ntile) * 128;
  int bm = (blockIdx.x / ntile) * 128;
  f32x4 acc[4][4];
  gemm_bt_main(Yb, W2t, 1024, bm, bn, lds, acc);
  const int tid = threadIdx.x, wave = tid >> 6, lane = tid & 63;
  const int quad = lane >> 4, col = lane & 15;
  const int wm = (wave & 1) * 64, wn = (wave >> 1) * 64;
  for (int i = 0; i < 4; ++i) {
    int row0 = bm + wm + i * 16 + quad * 4;
    for (int j = 0; j < 4; ++j) {
      int cg = bn + wn + j * 16 + col;
      float bv = bias[cg];
      for (int r = 0; r < 4; ++r)
        out[(size_t)(row0 + r) * 1024 + cg] = acc[i][j][r] + bv;
    }
  }
}

// ---------------- flash attention, transposed-S, balanced persistent ----------
// (unchanged from R5 — verified; see R2/R3 notes)
#define KS_OFF 0      // K tile [128][72] elems
#define VS_OFF 9216   // V tile [64][136] elems, k-permuted within 32-groups
__global__ __launch_bounds__(256, 2) void attn(
    const ushort_t* __restrict__ Qb, const ushort_t* __restrict__ Kb,
    const ushort_t* __restrict__ Vtb, ushort_t* __restrict__ Yb) {
  __shared__ ushort_t lds[17920];  // 35840 B
  const int tid = threadIdx.x, wave = tid >> 6, lane = tid & 63;
  const int quad = lane >> 4, col = lane & 15;
  const int bh = blockIdx.x & 63;
  const int a = blockIdx.x >> 6;  // 0..7
  const int b = bh >> 4, h = bh & 15;
  const ushort_t* Qg = Qb + (size_t)bh * 2048 * 64;
  const ushort_t* Kg = Kb + (size_t)bh * 2048 * 64;
  const ushort_t* Vg = Vtb + (size_t)bh * 64 * 2048;
  const int kv = tid;
  f32x4 z = {0.f, 0.f, 0.f, 0.f};

  for (int item = 0; item < 2; ++item) {
    const int qt = item == 0 ? 15 - a : a;
    const int q0 = qt * 128;
    short8 qf[2][2];
    for (int i = 0; i < 2; ++i)
      for (int ks = 0; ks < 2; ++ks)
        qf[i][ks] = *(const short8*)(
            Qg + (size_t)(q0 + wave * 32 + i * 16 + col) * 64 + ks * 32 + quad * 8);
    short8 kpre[4], vpre[4];
#pragma unroll
    for (int it = 0; it < 4; ++it) {
      int v = it * 256 + kv;
      kpre[it] = *(const short8*)(Kg + (size_t)(0 + (v >> 3)) * 64 + (v & 7) * 8);
      vpre[it] = *(const short8*)(Vg + (size_t)(v >> 4) * 2048 + 0 + (v & 15) * 8);
    }

    f32x4 oacc[2][4];
    float mst[2] = {-3.0e38f, -3.0e38f}, lst[2] = {0.f, 0.f};
    for (int i = 0; i < 2; ++i)
      for (int dt = 0; dt < 4; ++dt) oacc[i][dt] = z;

    for (int kt = 0; kt <= qt; ++kt) {
      int k0 = kt * 128;
      __syncthreads();
#pragma unroll
      for (int it = 0; it < 4; ++it) {
        int v = it * 256 + kv;
        *(short8*)(lds + KS_OFF + (v >> 3) * 72 + (v & 7) * 8) = kpre[it];
      }
#pragma unroll
      for (int it = 0; it < 4; ++it) {
        int v = it * 256 + kv;
        int d = v >> 4, kc = (v & 15) * 8;
        int p = kc >> 5, u = (kc >> 4) & 1, g0 = (kc >> 2) & 3;
        int pos1 = p * 32 + g0 * 8 + u * 4;
        short8 val = vpre[it];
        ushort4 lo4, hi4;
        lo4.x = (ushort_t)val[0]; lo4.y = (ushort_t)val[1];
        lo4.z = (ushort_t)val[2]; lo4.w = (ushort_t)val[3];
        hi4.x = (ushort_t)val[4]; hi4.y = (ushort_t)val[5];
        hi4.z = (ushort_t)val[6]; hi4.w = (ushort_t)val[7];
        *(ushort4*)(lds + VS_OFF + d * 136 + pos1) = lo4;
        *(ushort4*)(lds + VS_OFF + d * 136 + pos1 + 8) = hi4;
      }
      __syncthreads();
      if (kt < qt) {
        int k0n = k0 + 128;
#pragma unroll
        for (int it = 0; it < 4; ++it) {
          int v = it * 256 + kv;
          kpre[it] = *(const short8*)(Kg + (size_t)(k0n + (v >> 3)) * 64 + (v & 7) * 8);
          vpre[it] = *(const short8*)(Vg + (size_t)(v >> 4) * 2048 + k0n + (v & 15) * 8);
        }
      }
      f32x4 s[2][8];
      for (int i = 0; i < 2; ++i)
        for (int j = 0; j < 8; ++j) s[i][j] = z;
      for (int j = 0; j < 8; ++j) {
        short8 kf0 = *(const short8*)(lds + KS_OFF + (j * 16 + col) * 72 + quad * 8);
        short8 kf1 = *(const short8*)(lds + KS_OFF + (j * 16 + col) * 72 + 32 + quad * 8);
        for (int i = 0; i < 2; ++i) {
          s[i][j] = __builtin_amdgcn_mfma_f32_16x16x32_bf16(kf0, qf[i][0], s[i][j], 0, 0, 0);
          s[i][j] = __builtin_amdgcn_mfma_f32_16x16x32_bf16(kf1, qf[i][1], s[i][j], 0, 0, 0);
        }
      }
      if (kt == qt) {
        for (int i = 0; i < 2; ++i) {
          int qg = q0 + wave * 32 + i * 16 + col;
          for (int j = 0; j < 8; ++j) {
            int kg = k0 + j * 16 + quad * 4;
            for (int r = 0; r < 4; ++r)
              if (kg + r > qg) s[i][j][r] = -3.0e38f;
          }
        }
      }
      for (int i = 0; i < 2; ++i) {
        f32x4 vm = s[i][0];
        for (int j = 1; j < 8; ++j)
          for (int r = 0; r < 4; ++r) vm[r] = fmaxf(vm[r], s[i][j][r]);
        float rm = fmaxf(fmaxf(vm[0], vm[1]), fmaxf(vm[2], vm[3]));
        rm = fmaxf(rm, __shfl_xor(rm, 16));
        rm = fmaxf(rm, __shfl_xor(rm, 32));
        float mnew = fmaxf(mst[i], rm);
        float alpha = __builtin_amdgcn_exp2f(mst[i] - mnew);
        mst[i] = mnew;
        float rs = 0.f;
        for (int j = 0; j < 8; ++j)
          for (int r = 0; r < 4; ++r) {
            float p = __builtin_amdgcn_exp2f(s[i][j][r] - mnew);
            s[i][j][r] = p;
            rs += p;
          }
        rs += __shfl_xor(rs, 16);
        rs += __shfl_xor(rs, 32);
        lst[i] = lst[i] * alpha + rs;
        for (int dt = 0; dt < 4; ++dt)
          for (int r = 0; r < 4; ++r) oacc[i][dt][r] *= alpha;
      }
      for (int p2 = 0; p2 < 4; ++p2) {
        short8 pf[2];
        for (int i = 0; i < 2; ++i) {
          uint4v w;
          w[0] = pk2(s[i][2 * p2][1], s[i][2 * p2][0]);
          w[1] = pk2(s[i][2 * p2][3], s[i][2 * p2][2]);
          w[2] = pk2(s[i][2 * p2 + 1][1], s[i][2 * p2 + 1][0]);
          w[3] = pk2(s[i][2 * p2 + 1][3], s[i][2 * p2 + 1][2]);
          pf[i] = *(short8*)&w;
        }
        for (int dt = 0; dt < 4; ++dt) {
          short8 vf = *(const short8*)(lds + VS_OFF + (dt * 16 + col) * 136 + p2 * 32 + quad * 8);
          for (int i = 0; i < 2; ++i)
            oacc[i][dt] = __builtin_amdgcn_mfma_f32_16x16x32_bf16(vf, pf[i], oacc[i][dt], 0, 0, 0);
        }
      }
    }
    for (int i = 0; i < 2; ++i) {
      float linv = 1.0f / lst[i];
      int t = q0 + wave * 32 + i * 16 + col;
      size_t base = ((size_t)(b * 2048 + t)) * 1024 + h * 64;
      for (int dt = 0; dt < 4; ++dt) {
        ushort4 pk;
        pk.x = f2bf(oacc[i][dt][0] * linv);
        pk.y = f2bf(oacc[i][dt][1] * linv);
        pk.z = f2bf(oacc[i][dt][2] * linv);
        pk.w = f2bf(oacc[i][dt][3] * linv);
        *(ushort4*)(Yb + base + dt * 16 + quad * 4) = pk;
      }
    }
  }
}

extern "C" void kernel_launch(void* const* d_in, const int* in_sizes, int n_in,
                              void* d_out, int out_size, void* d_ws, size_t ws_size,
                              hipStream_t stream) {
  const float* x     = (const float*)d_in[0];
  const float* qkv_w = (const float*)d_in[1];
  const float* qkv_b = (const float*)d_in[2];
  const float* o_w   = (const float*)d_in[3];
  const float* o_b   = (const float*)d_in[4];
  float* out = (float*)d_out;
  char* ws = (char*)d_ws;
  ushort_t* Xb  = (ushort_t*)(ws);              // 16 MB (aliased as Yb later)
  ushort_t* W1t = (ushort_t*)(ws + 16777216);   // 6 MB  [3072][1024]
  ushort_t* W2t = (ushort_t*)(ws + 23068672);   // 2 MB  [1024][1024]
  ushort_t* Qb  = (ushort_t*)(ws + 25165824);   // 16 MB [64][2048][64] (pre-scaled)
  ushort_t* Kb  = (ushort_t*)(ws + 41943040);   // 16 MB
  ushort_t* Vtb = (ushort_t*)(ws + 58720256);   // 16 MB [64][64][2048]
  ushort_t* Yb  = Xb;                           // alias: X dead after gemm_qkv

  prep<<<5120, 256, 0, stream>>>(x, Xb, qkv_w, W1t, o_w, W2t);
  gemm_qkv<<<768, 512, 0, stream>>>(Xb, W1t, qkv_b, Qb, Kb, Vtb);
  attn<<<512, 256, 0, stream>>>(Qb, Kb, Vtb, Yb);
  gemm_out_k<<<512, 256, 0, stream>>>(Yb, W2t, o_b, out);
}